// Round 13
// baseline (299.568 us; speedup 1.0000x reference)
//
#include <hip/hip_runtime.h>

#define N_ 8
#define C_ 512
#define S_ 2048
#define H_ 8
#define D_ 64
#define CS_ (C_*S_)
#define EPSV 1e-5f
#define SCALEQ 0.1803368801f   /* 0.125 * log2(e): scores in log2 domain */

typedef __bf16 bf16x8 __attribute__((ext_vector_type(8)));
typedef float  f32x4  __attribute__((ext_vector_type(4)));

#define MFMA16(a,b,c) __builtin_amdgcn_mfma_f32_16x16x32_bf16((a),(b),(c),0,0,0)

#if __has_builtin(__builtin_amdgcn_exp2f)
#define EXP2(x) __builtin_amdgcn_exp2f(x)
#else
#define EXP2(x) __expf((x)*0.69314718056f)
#endif

// async global->LDS 16B per lane; LDS dest is wave-uniform base + lane*16
#define GLOAD_LDS16(gp, lp)                                                   \
    __builtin_amdgcn_global_load_lds(                                         \
        (const __attribute__((address_space(1))) void*)(gp),                  \
        (__attribute__((address_space(3))) void*)(lp), 16, 0, 0)

__device__ __forceinline__ unsigned short f2b(float f){
    __bf16 h = (__bf16)f;                    // native v_cvt (RNE)
    return __builtin_bit_cast(unsigned short, h);
}
__device__ __forceinline__ unsigned pk2(float a, float b){
    return (unsigned)f2b(a) | ((unsigned)f2b(b) << 16);
}

// quad redistribution primitive: (x,y) -> P16(P32(x,y)).
// Net: x''=(x.q0,x.q2,y.q0,y.q2) per quad, y''=(x.q1,x.q3,y.q1,y.q3).
__device__ __forceinline__ void quad_swap(unsigned &x, unsigned &y){
#if __has_builtin(__builtin_amdgcn_permlane32_swap) && __has_builtin(__builtin_amdgcn_permlane16_swap)
    auto r = __builtin_amdgcn_permlane32_swap(x, y, false, false);
    auto u = __builtin_amdgcn_permlane16_swap(r[0], r[1], false, false);
    x = u[0]; y = u[1];
#else
    asm volatile("s_nop 1\n\t"
                 "v_permlane32_swap_b32 %0, %1\n\t"
                 "s_nop 1\n\t"
                 "v_permlane16_swap_b32 %0, %1\n\t"
                 "s_nop 1"
                 : "+v"(x), "+v"(y));
#endif
}

// ---------------- K1: per-sample partial sum / sumsq (no atomics, no memset)
__global__ __launch_bounds__(256)
void k_stats(const float* __restrict__ x, float* __restrict__ statsp){
    int n = blockIdx.x >> 6;
    const uint4* b4 = (const uint4*)(x + (size_t)n * CS_
                                       + (size_t)(blockIdx.x & 63) * (CS_/64));
    float s = 0.f, s2 = 0.f;
    #pragma unroll
    for (int i = 0; i < 16; ++i) {
        uint4 v = b4[threadIdx.x + i*256];
        const float* p = (const float*)&v;
        #pragma unroll
        for (int j = 0; j < 4; ++j) { float f = p[j]; s += f; s2 += f*f; }
    }
    for (int off = 32; off; off >>= 1) {
        s  += __shfl_down(s,  off, 64);
        s2 += __shfl_down(s2, off, 64);
    }
    __shared__ float ls[4], ls2[4];
    int w = threadIdx.x >> 6, l = threadIdx.x & 63;
    if (l == 0) { ls[w] = s; ls2[w] = s2; }
    __syncthreads();
    if (threadIdx.x == 0) {
        statsp[2*blockIdx.x + 0] = ls[0]+ls[1]+ls[2]+ls[3];
        statsp[2*blockIdx.x + 1] = ls2[0]+ls2[1]+ls2[2]+ls2[3];
    }
}

// ---------------- K2: groupnorm + transpose to xn_t[n][s][c] bf16 ----------
// Reduces the 64 per-chunk partials itself (uniform scalar loads).
__global__ __launch_bounds__(256)
void k_norm_t(const float* __restrict__ x,
              const float* __restrict__ gw,
              const float* __restrict__ gb,
              const float* __restrict__ statsp,
              unsigned short* __restrict__ xnt){
    int n = blockIdx.z, cb = blockIdx.y, sb = blockIdx.x;
    const float* sp = statsp + n*128;
    float s = 0.f, s2 = 0.f;
    #pragma unroll 8
    for (int i = 0; i < 64; ++i) { s += sp[2*i]; s2 += sp[2*i+1]; }
    float mean = s * (1.f/CS_);
    float var  = s2 * (1.f/CS_) - mean*mean;
    float inv  = rsqrtf(var + EPSV);
    __shared__ unsigned short tile[64][72];
    int t = threadIdx.x;
    int ci = t >> 2;
    int sj = (t & 3) * 16;
    int c  = cb*64 + ci;
    float w = gw[c] * inv;
    float b = gb[c] - mean * w;
    const float* src = x + ((size_t)n*C_ + c) * S_ + sb*64 + sj;
    #pragma unroll
    for (int q = 0; q < 4; ++q) {
        uint4 v = ((const uint4*)src)[q];
        const float* pf = (const float*)&v;
        #pragma unroll
        for (int j = 0; j < 4; ++j) tile[ci][sj + q*4 + j] = f2b(pf[j]*w + b);
    }
    __syncthreads();
    int si = t >> 2;
    int cj = (t & 3) * 16;
    unsigned short o[16];
    #pragma unroll
    for (int j = 0; j < 16; ++j) o[j] = tile[cj+j][si];
    unsigned short* dst = xnt + ((size_t)n*S_ + sb*64 + si) * C_ + cb*64 + cj;
    *(uint4*)dst       = *(const uint4*)&o[0];
    *(uint4*)(dst + 8) = *(const uint4*)&o[8];
}

// ---------------- K3: QKV GEMM, 128x128 tile, BK=32. W staged DIRECTLY from
// fp32 (in-register pk2 convert -> LDS); B (xnt bf16) via global_load_lds.
// Dense LDS-bounce epilogue (r8, measured). Removes the k_convert dispatch. --
__global__ __launch_bounds__(256)
void k_qkv(const float* __restrict__ Wf,
           const float* __restrict__ bias,
           const unsigned short* __restrict__ xnt,
           unsigned short* __restrict__ qkT,
           unsigned short* __restrict__ vbuf){
    const int n  = blockIdx.z;
    const int m0 = blockIdx.y * 128;
    const int s0 = blockIdx.x * 128;
    const bool tr = (blockIdx.y < 8);   // q/k rows (o<1024): transposed epilogue
    const int t = threadIdx.x, wv = t>>6, l = t&63, quad = l>>4, l16 = l&15;
    const int wr = (wv>>1)*64, wc = (wv&1)*64;
    // 32 KB: staging As[128][32]@0, Bs@4096 (linear, unpadded);
    // after the K-loop the whole block is reused as 4x (64x64) per-wave scratch.
    __shared__ unsigned short sh[16384];
    unsigned short* As = sh;
    unsigned short* Bs = sh + 4096;
    f32x4 zero = {0.f,0.f,0.f,0.f};
    f32x4 acc[4][4];
    #pragma unroll
    for (int i=0;i<4;++i)
        #pragma unroll
        for (int j=0;j<4;++j) acc[i][j] = zero;
    const float* Abase = Wf + (size_t)m0*C_;
    const unsigned short* Bbase = xnt + ((size_t)n*S_ + s0) * C_;
    const int arow = t >> 1, ahalf = (t & 1) * 16;   // fp32 elements
    const int grow = l >> 2, gcol = (l & 3) * 8;     // B chunk geometry
    for (int k0 = 0; k0 < C_; k0 += 32) {
        __syncthreads();                    // prev slab's frag reads complete
        {   // A: fp32 load -> bf16 convert -> LDS (16 floats/thread)
            const float* ap = Abase + (size_t)arow*C_ + k0 + ahalf;
            float4 f0 = ((const float4*)ap)[0], f1 = ((const float4*)ap)[1];
            float4 f2 = ((const float4*)ap)[2], f3 = ((const float4*)ap)[3];
            uint4 w0 = { pk2(f0.x,f0.y), pk2(f0.z,f0.w),
                         pk2(f1.x,f1.y), pk2(f1.z,f1.w) };
            uint4 w1 = { pk2(f2.x,f2.y), pk2(f2.z,f2.w),
                         pk2(f3.x,f3.y), pk2(f3.z,f3.w) };
            *(uint4*)&As[arow*32 + ahalf]     = w0;
            *(uint4*)&As[arow*32 + ahalf + 8] = w1;
            // B: async bf16 chunks (wave-uniform LDS dest)
            #pragma unroll
            for (int j=0;j<2;++j){
                int c = wv*2 + j;
                GLOAD_LDS16(Bbase + (size_t)(c*16 + grow)*C_ + k0 + gcol,
                            &Bs[c*512]);
            }
        }
        __syncthreads();                    // vm+lgkm drained before barrier
        bf16x8 af[4], bfg[4];
        #pragma unroll
        for (int ms=0; ms<4; ++ms) af[ms]  = *(const bf16x8*)&As[(wr+ms*16+l16)*32 + quad*8];
        #pragma unroll
        for (int ns=0; ns<4; ++ns) bfg[ns] = *(const bf16x8*)&Bs[(wc+ns*16+l16)*32 + quad*8];
        if (tr) {
            #pragma unroll
            for (int ms=0; ms<4; ++ms)
                #pragma unroll
                for (int ns=0; ns<4; ++ns)
                    acc[ms][ns] = MFMA16(bfg[ns], af[ms], acc[ms][ns]);  // D rows = s
        } else {
            #pragma unroll
            for (int ms=0; ms<4; ++ms)
                #pragma unroll
                for (int ns=0; ns<4; ++ns)
                    acc[ms][ns] = MFMA16(af[ms], bfg[ns], acc[ms][ns]);  // D rows = o
        }
    }
    __syncthreads();                         // all waves done reading As/Bs
    unsigned short* scr = sh + wv*4096;      // 64x64 shorts per wave
    if (tr) {
        // acc[ms][ns][r]: s_local = ns*16+quad*4+r, d = ms*16+l16 (one g per wave)
        const int g = (m0 + wr) >> 6;
        const float scl = (blockIdx.y < 4) ? SCALEQ : 1.f;
        #pragma unroll
        for (int ms=0; ms<4; ++ms) {
            float bia = bias[m0 + wr + ms*16 + l16];
            #pragma unroll
            for (int ns=0; ns<4; ++ns)
                #pragma unroll
                for (int r=0; r<4; ++r)
                    scr[(ns*16 + quad*4 + r)*64 + ms*16 + l16] =
                        f2b((acc[ms][ns][r] + bia) * scl);
        }
        __asm__ __volatile__("s_waitcnt lgkmcnt(0)" ::: "memory");  // own-wave scratch
        unsigned short* dst = qkT + (((size_t)n*16 + g)*S_ + s0 + wc)*64;
        #pragma unroll
        for (int pass=0; pass<8; ++pass) {
            int sl = pass*8 + (l>>3);
            *(uint4*)&dst[(size_t)sl*64 + (l&7)*8] =
                *(const uint4*)&scr[sl*64 + (l&7)*8];   // 8 full 128B lines/instr
        }
    } else {
        // acc[ms][ns][r]: o_local = ms*16+quad*4+r, s_local = ns*16+l16
        #pragma unroll
        for (int ms=0; ms<4; ++ms)
            #pragma unroll
            for (int ns=0; ns<4; ++ns)
                #pragma unroll
                for (int r=0; r<4; ++r) {
                    int o = m0 + wr + ms*16 + quad*4 + r;
                    scr[(ms*16 + quad*4 + r)*64 + ns*16 + l16] =
                        f2b(acc[ms][ns][r] + bias[o]);
                }
        __asm__ __volatile__("s_waitcnt lgkmcnt(0)" ::: "memory");
        unsigned short* vbase = vbuf + ((size_t)(n*512 + (m0-1024) + wr))*S_ + s0 + wc;
        #pragma unroll
        for (int pass=0; pass<8; ++pass) {
            int vo = pass*8 + (l>>3);
            *(uint4*)&vbase[(size_t)vo*S_ + (l&7)*8] =
                *(const uint4*)&scr[vo*64 + (l&7)*8];   // 128B dense per o-row
        }
    }
}

// ---------------- K4: flash attention (r8 code, measured 107-114us; frozen).
// S^T = K Q^T; P in registers (permlane quad redistribution); lsum on the
// matrix pipe; Ks/Vs double-buffered, one barrier per tile; T14 reg-prefetch.
__global__ __launch_bounds__(256)
void k_attn(const unsigned short* __restrict__ qkT,
            const unsigned short* __restrict__ vbuf,
            unsigned short* __restrict__ yt){
    const int head = blockIdx.x & 63;       // n*8+h  (XCD swizzle: head -> XCD)
    const int qt   = blockIdx.x >> 6;       // 0..15
    const int n = head >> 3, h = head & 7;
    const int t = threadIdx.x, wv = t>>6, l = t&63, quad = l>>4, l16 = l&15;
    const unsigned short* Q = qkT + (((size_t)n*16 + h    )*S_)*64;
    const unsigned short* K = qkT + (((size_t)n*16 + 8 + h)*S_)*64;
    const unsigned short* V = vbuf + ((size_t)n*512 + h*64)*S_;
    __shared__ unsigned short Ks[2][64][72];    // [buf][key][d]
    __shared__ unsigned short Vs[2][64][72];    // [buf][d][key]
    const int qbase = qt*128 + wv*32;
    bf16x8 qf[2][2];
    #pragma unroll
    for (int mt=0; mt<2; ++mt)
        #pragma unroll
        for (int kk=0; kk<2; ++kk)
            qf[mt][kk] = *(const bf16x8*)&Q[(size_t)(qbase+mt*16+l16)*64 + kk*32 + quad*8];
    f32x4 zero = {0.f,0.f,0.f,0.f};
    f32x4 oacc[2][4];
    f32x4 lacc[2] = {zero, zero};
    #pragma unroll
    for (int mt=0;mt<2;++mt)
        #pragma unroll
        for (int dt=0;dt<4;++dt) oacc[mt][dt]=zero;
    bf16x8 onesv;
    #pragma unroll
    for (int i=0;i<8;++i) onesv[i] = (__bf16)1.0f;

    // staging geometry: each thread stages 2 K rows + 2 V rows (16B each).
    const int r0 = t >> 3;              // 0..31
    const int c0 = (t & 7) * 8;         // 0..56 shorts
    const int kOff = r0*64 + c0;
    const int vOff = r0*S_ + c0;
    uint4 ka, kb, va, vb;
    // tile 0 -> buf0
    ka = *(const uint4*)(K + kOff);
    kb = *(const uint4*)(K + kOff + 32*64);
    va = *(const uint4*)(V + vOff);
    vb = *(const uint4*)(V + vOff + (size_t)32*S_);
    *(uint4*)&Ks[0][r0][c0]    = ka;
    *(uint4*)&Ks[0][r0+32][c0] = kb;
    *(uint4*)&Vs[0][r0][c0]    = va;
    *(uint4*)&Vs[0][r0+32][c0] = vb;
    // issue tile 1 (lands in regs during first compute)
    ka = *(const uint4*)(K + 4096 + kOff);
    kb = *(const uint4*)(K + 4096 + kOff + 32*64);
    va = *(const uint4*)(V + 64 + vOff);
    vb = *(const uint4*)(V + 64 + vOff + (size_t)32*S_);
    __syncthreads();

#define ATTN_STEP(RB, WB, KT, DOW, DOL) do {                                   \
    if (DOW) {                                                                 \
        *(uint4*)&Ks[WB][r0][c0]    = ka;  /* vmcnt wait inserted */           \
        *(uint4*)&Ks[WB][r0+32][c0] = kb;                                      \
        *(uint4*)&Vs[WB][r0][c0]    = va;                                      \
        *(uint4*)&Vs[WB][r0+32][c0] = vb;                                      \
        if (DOL) {                                                             \
            const unsigned short* kp = K + (size_t)((KT)+2)*4096;              \
            const unsigned short* vp = V + (size_t)((KT)+2)*64;                \
            ka = *(const uint4*)(kp + kOff);                                   \
            kb = *(const uint4*)(kp + kOff + 32*64);                           \
            va = *(const uint4*)(vp + vOff);                                   \
            vb = *(const uint4*)(vp + vOff + (size_t)32*S_);                   \
        }                                                                      \
    }                                                                          \
    _Pragma("unroll")                                                          \
    for (int ks=0; ks<2; ++ks) {                                               \
        unsigned wp[2][2][2];   /* [ntoff][mt][word] */                        \
        _Pragma("unroll")                                                      \
        for (int ntoff=0; ntoff<2; ++ntoff) {                                  \
            const int nt = 2*ks + ntoff;                                       \
            bf16x8 kf0 = *(const bf16x8*)&Ks[RB][nt*16 + l16][quad*8];         \
            bf16x8 kf1 = *(const bf16x8*)&Ks[RB][nt*16 + l16][32 + quad*8];    \
            _Pragma("unroll")                                                  \
            for (int mt=0; mt<2; ++mt) {                                       \
                f32x4 s = MFMA16(kf0, qf[mt][0], zero);                        \
                s = MFMA16(kf1, qf[mt][1], s);                                 \
                /* s[r] = S^T[key=nt*16+quad*4+r][q=mt*16+l16], log2 domain */ \
                wp[ntoff][mt][0] = pk2(EXP2(s[0]), EXP2(s[1]));                \
                wp[ntoff][mt][1] = pk2(EXP2(s[2]), EXP2(s[3]));                \
            }                                                                  \
        }                                                                      \
        bf16x8 pf[2];                                                          \
        _Pragma("unroll")                                                      \
        for (int mt=0; mt<2; ++mt) {                                           \
            unsigned a0 = wp[0][mt][0], b0 = wp[1][mt][0];                     \
            unsigned a1 = wp[0][mt][1], b1 = wp[1][mt][1];                     \
            quad_swap(a0, b0);                                                 \
            quad_swap(a1, b1);                                                 \
            uint4 pw = {a0, a1, b0, b1};                                       \
            pf[mt] = __builtin_bit_cast(bf16x8, pw);                           \
        }                                                                      \
        lacc[0] = MFMA16(onesv, pf[0], lacc[0]);                               \
        lacc[1] = MFMA16(onesv, pf[1], lacc[1]);                               \
        _Pragma("unroll")                                                      \
        for (int dt=0; dt<4; ++dt) {                                           \
            bf16x8 vf = *(const bf16x8*)&Vs[RB][dt*16 + l16][ks*32 + quad*8];  \
            oacc[0][dt] = MFMA16(vf, pf[0], oacc[0][dt]);                      \
            oacc[1][dt] = MFMA16(vf, pf[1], oacc[1][dt]);                      \
        }                                                                      \
    }                                                                          \
    __syncthreads();                                                           \
} while(0)

    for (int kt2 = 0; kt2 < 15; ++kt2) {
        const int kt0 = kt2*2;
        ATTN_STEP(0, 1, kt0,   1, 1);
        ATTN_STEP(1, 0, kt0+1, 1, 1);
    }
    ATTN_STEP(0, 1, 30, 1, 0);   // write tile 31, no further loads
    ATTN_STEP(1, 0, 31, 0, 0);   // pure compute
#undef ATTN_STEP

    // lacc rows are identical (ones-A): lane's denom for q=mt*16+l16 is lacc[mt][0]
    float inv[2] = { 1.f / lacc[0][0], 1.f / lacc[1][0] };
    unsigned short* dst = yt + ((size_t)n*S_)*C_;
    #pragma unroll
    for (int mt=0; mt<2; ++mt) {
        int qr = qbase + mt*16 + l16;
        #pragma unroll
        for (int dt=0; dt<4; ++dt) {
            uint2 pk = { pk2(oacc[mt][dt][0]*inv[mt], oacc[mt][dt][1]*inv[mt]),
                         pk2(oacc[mt][dt][2]*inv[mt], oacc[mt][dt][3]*inv[mt]) };
            *(uint2*)&dst[(size_t)qr*C_ + h*64 + dt*16 + quad*4] = pk;
        }
    }
}

// ---------------- K5: out projection, 128x128 tile, BK=32. W staged DIRECTLY
// from fp32 (in-register convert); B (yt bf16) via global_load_lds.
// + bias + residual -> fp32 (full-line stores). Removes k_convert dispatch. --
__global__ __launch_bounds__(256)
void k_out(const float* __restrict__ Wf,
           const float* __restrict__ bias,
           const unsigned short* __restrict__ yt,
           const float* __restrict__ inpt,
           float* __restrict__ out){
    const int n  = blockIdx.z;
    const int m0 = blockIdx.y * 128;
    const int s0 = blockIdx.x * 128;
    const int t = threadIdx.x, wv = t>>6, l = t&63, quad = l>>4, l16 = l&15;
    const int wr = (wv>>1)*64, wc = (wv&1)*64;
    __shared__ unsigned short sh[8192];      // As[128][32]@0, Bs@4096 (16 KB)
    unsigned short* As = sh;
    unsigned short* Bs = sh + 4096;
    f32x4 zero = {0.f,0.f,0.f,0.f};
    f32x4 acc[4][4];
    #pragma unroll
    for (int i=0;i<4;++i)
        #pragma unroll
        for (int j=0;j<4;++j) acc[i][j] = zero;
    const float* Abase = Wf + (size_t)m0*C_;
    const unsigned short* Bbase = yt + ((size_t)n*S_ + s0) * C_;
    const int arow = t >> 1, ahalf = (t & 1) * 16;
    const int grow = l >> 2, gcol = (l & 3) * 8;
    for (int k0 = 0; k0 < C_; k0 += 32) {
        __syncthreads();
        {
            const float* ap = Abase + (size_t)arow*C_ + k0 + ahalf;
            float4 f0 = ((const float4*)ap)[0], f1 = ((const float4*)ap)[1];
            float4 f2 = ((const float4*)ap)[2], f3 = ((const float4*)ap)[3];
            uint4 w0 = { pk2(f0.x,f0.y), pk2(f0.z,f0.w),
                         pk2(f1.x,f1.y), pk2(f1.z,f1.w) };
            uint4 w1 = { pk2(f2.x,f2.y), pk2(f2.z,f2.w),
                         pk2(f3.x,f3.y), pk2(f3.z,f3.w) };
            *(uint4*)&As[arow*32 + ahalf]     = w0;
            *(uint4*)&As[arow*32 + ahalf + 8] = w1;
            #pragma unroll
            for (int j=0;j<2;++j){
                int c = wv*2 + j;
                GLOAD_LDS16(Bbase + (size_t)(c*16 + grow)*C_ + k0 + gcol,
                            &Bs[c*512]);
            }
        }
        __syncthreads();
        bf16x8 af[4], bfg[4];
        #pragma unroll
        for (int ms=0; ms<4; ++ms) af[ms]  = *(const bf16x8*)&As[(wr+ms*16+l16)*32 + quad*8];
        #pragma unroll
        for (int ns=0; ns<4; ++ns) bfg[ns] = *(const bf16x8*)&Bs[(wc+ns*16+l16)*32 + quad*8];
        #pragma unroll
        for (int ms=0; ms<4; ++ms)
            #pragma unroll
            for (int ns=0; ns<4; ++ns)
                acc[ms][ns] = MFMA16(af[ms], bfg[ns], acc[ms][ns]);
    }
    #pragma unroll
    for (int ms=0; ms<4; ++ms)
        #pragma unroll
        for (int ns=0; ns<4; ++ns)
            #pragma unroll
            for (int r=0; r<4; ++r) {
                int o = m0 + wr + ms*16 + quad*4 + r;
                int s = s0 + wc + ns*16 + l16;
                size_t idx = ((size_t)n*C_ + o)*S_ + s;
                out[idx] = acc[ms][ns][r] + bias[o] + inpt[idx];
            }
}

extern "C" void kernel_launch(void* const* d_in, const int* in_sizes, int n_in,
                              void* d_out, int out_size, void* d_ws, size_t ws_size,
                              hipStream_t stream) {
    (void)in_sizes; (void)n_in; (void)out_size; (void)ws_size;
    const float* inpt  = (const float*)d_in[0];
    const float* gn_w  = (const float*)d_in[1];
    const float* gn_b  = (const float*)d_in[2];
    const float* qkv_w = (const float*)d_in[3];
    const float* qkv_b = (const float*)d_in[4];
    const float* out_w = (const float*)d_in[5];
    const float* out_b = (const float*)d_in[6];
    float* out = (float*)d_out;

    // ws (48 MiB): xnt [0,16M) (->yt), qkT [16M,48M). statsp (4 KB partials)
    // overlaps qkT tail (temporally disjoint: consumed by k_norm_t before
    // k_qkv writes qkT). d_out lends vbuf [0,16M) (dead before k_out).
    // 5 dispatches total (was 8): W converts fused into the GEMM staging,
    // memset eliminated via partial-sum stats.
    char* ws = (char*)d_ws;
    unsigned short* xnt    = (unsigned short*)ws;
    unsigned short* qkT    = (unsigned short*)(ws + ((size_t)16 << 20));
    float*          statsp = (float*)(ws + ((size_t)48 << 20) - 4096);
    unsigned short* vbuf   = (unsigned short*)d_out;
    unsigned short* yt     = xnt;

    k_stats <<<dim3(N_*64),             256, 0, stream>>>(inpt, statsp);
    k_norm_t<<<dim3(S_/64, C_/64, N_),  256, 0, stream>>>(inpt, gn_w, gn_b, statsp, xnt);
    k_qkv   <<<dim3(S_/128, 12, N_),    256, 0, stream>>>(qkv_w, qkv_b, xnt, qkT, vbuf);
    k_attn  <<<dim3(1024),              256, 0, stream>>>(qkT, vbuf, yt);
    k_out   <<<dim3(S_/128, 4, N_),     256, 0, stream>>>(out_w, out_b, yt, inpt, out);
}

// Round 14
// 269.026 us; speedup vs baseline: 1.1135x; 1.1135x over previous
//
#include <hip/hip_runtime.h>

#define N_ 8
#define C_ 512
#define S_ 2048
#define H_ 8
#define D_ 64
#define CS_ (C_*S_)
#define EPSV 1e-5f
#define SCALEQ 0.1803368801f   /* 0.125 * log2(e): scores in log2 domain */

typedef __bf16 bf16x8 __attribute__((ext_vector_type(8)));
typedef float  f32x4  __attribute__((ext_vector_type(4)));

#define MFMA16(a,b,c) __builtin_amdgcn_mfma_f32_16x16x32_bf16((a),(b),(c),0,0,0)

#if __has_builtin(__builtin_amdgcn_exp2f)
#define EXP2(x) __builtin_amdgcn_exp2f(x)
#else
#define EXP2(x) __expf((x)*0.69314718056f)
#endif

__device__ __forceinline__ unsigned short f2b(float f){
    __bf16 h = (__bf16)f;                    // native v_cvt (RNE)
    return __builtin_bit_cast(unsigned short, h);
}
__device__ __forceinline__ unsigned pk2(float a, float b){
    return (unsigned)f2b(a) | ((unsigned)f2b(b) << 16);
}

// quad redistribution primitive: (x,y) -> P16(P32(x,y)).
// Net: x''=(x.q0,x.q2,y.q0,y.q2) per quad, y''=(x.q1,x.q3,y.q1,y.q3).
__device__ __forceinline__ void quad_swap(unsigned &x, unsigned &y){
#if __has_builtin(__builtin_amdgcn_permlane32_swap) && __has_builtin(__builtin_amdgcn_permlane16_swap)
    auto r = __builtin_amdgcn_permlane32_swap(x, y, false, false);
    auto u = __builtin_amdgcn_permlane16_swap(r[0], r[1], false, false);
    x = u[0]; y = u[1];
#else
    asm volatile("s_nop 1\n\t"
                 "v_permlane32_swap_b32 %0, %1\n\t"
                 "s_nop 1\n\t"
                 "v_permlane16_swap_b32 %0, %1\n\t"
                 "s_nop 1"
                 : "+v"(x), "+v"(y));
#endif
}

// ---------------- K0: fp32 -> bf16 weight convert ----------------
__global__ __launch_bounds__(256)
void k_convert(const float* __restrict__ src, unsigned short* __restrict__ dst){
    int i = (blockIdx.x * 256 + threadIdx.x) * 4;
    uint4 v = *(const uint4*)(src + i);
    const float* pf = (const float*)&v;
    uint2 w = { pk2(pf[0], pf[1]), pk2(pf[2], pf[3]) };
    *(uint2*)(dst + i) = w;
}

// ---------------- K1: per-sample sum / sumsq ----------------
__global__ __launch_bounds__(256)
void k_stats(const float* __restrict__ x, float* __restrict__ stats){
    int n = blockIdx.x >> 6;
    int chunk = blockIdx.x & 63;
    const uint4* b4 = (const uint4*)(x + (size_t)n * CS_ + (size_t)chunk * (CS_/64));
    float s = 0.f, s2 = 0.f;
    #pragma unroll
    for (int i = 0; i < 16; ++i) {
        uint4 v = b4[threadIdx.x + i*256];
        const float* p = (const float*)&v;
        #pragma unroll
        for (int j = 0; j < 4; ++j) { float f = p[j]; s += f; s2 += f*f; }
    }
    for (int off = 32; off; off >>= 1) {
        s  += __shfl_down(s,  off, 64);
        s2 += __shfl_down(s2, off, 64);
    }
    __shared__ float ls[4], ls2[4];
    int w = threadIdx.x >> 6, l = threadIdx.x & 63;
    if (l == 0) { ls[w] = s; ls2[w] = s2; }
    __syncthreads();
    if (threadIdx.x == 0) {
        atomicAdd(&stats[n*2+0], ls[0]+ls[1]+ls[2]+ls[3]);
        atomicAdd(&stats[n*2+1], ls2[0]+ls2[1]+ls2[2]+ls2[3]);
    }
}

// ---------------- K2: groupnorm + transpose to xn_t[n][s][c] bf16 ----------------
__global__ __launch_bounds__(256)
void k_norm_t(const float* __restrict__ x,
              const float* __restrict__ gw,
              const float* __restrict__ gb,
              const float* __restrict__ stats,
              unsigned short* __restrict__ xnt){
    int n = blockIdx.z, cb = blockIdx.y, sb = blockIdx.x;
    float mean = stats[n*2+0] * (1.f/CS_);
    float var  = stats[n*2+1] * (1.f/CS_) - mean*mean;
    float inv  = rsqrtf(var + EPSV);
    __shared__ unsigned short tile[64][72];
    int t = threadIdx.x;
    int ci = t >> 2;
    int sj = (t & 3) * 16;
    int c  = cb*64 + ci;
    float w = gw[c] * inv;
    float b = gb[c] - mean * w;
    const float* src = x + ((size_t)n*C_ + c) * S_ + sb*64 + sj;
    #pragma unroll
    for (int q = 0; q < 4; ++q) {
        uint4 v = ((const uint4*)src)[q];
        const float* pf = (const float*)&v;
        #pragma unroll
        for (int j = 0; j < 4; ++j) tile[ci][sj + q*4 + j] = f2b(pf[j]*w + b);
    }
    __syncthreads();
    int si = t >> 2;
    int cj = (t & 3) * 16;
    unsigned short o[16];
    #pragma unroll
    for (int j = 0; j < 16; ++j) o[j] = tile[cj+j][si];
    unsigned short* dst = xnt + ((size_t)n*S_ + sb*64 + si) * C_ + cb*64 + cj;
    *(uint4*)dst       = *(const uint4*)&o[0];
    *(uint4*)(dst + 8) = *(const uint4*)&o[8];
}

// ---------------- K3: QKV GEMM, 128x128 tile, BK=32 padded LDS (r4 structure,
// measured-best), 4 waves (2x2), 4x4 frags/wave. Dense epilogue via per-wave
// LDS bounce (staging LDS reused after the K-loop). q pre-scaled by SCALEQ. --
__global__ __launch_bounds__(256)
void k_qkv(const unsigned short* __restrict__ Wb,
           const float* __restrict__ bias,
           const unsigned short* __restrict__ xnt,
           unsigned short* __restrict__ qkT,
           unsigned short* __restrict__ vbuf){
    const int n  = blockIdx.z;
    const int m0 = blockIdx.y * 128;
    const int s0 = blockIdx.x * 128;
    const bool tr = (blockIdx.y < 8);   // q/k rows (o<1024): transposed epilogue
    const int t = threadIdx.x, wv = t>>6, l = t&63, quad = l>>4, l16 = l&15;
    const int wr = (wv>>1)*64, wc = (wv&1)*64;
    // 32 KB shared: K-loop staging As[128][40]@0 / Bs[128][40]@5120 (20.5 KB);
    // after the loop the whole block is reused as 4x (64x64) per-wave scratch.
    __shared__ unsigned short sh[16384];
    unsigned short* As = sh;          // As[r][c] -> As[r*40+c]
    unsigned short* Bs = sh + 5120;
    f32x4 zero = {0.f,0.f,0.f,0.f};
    f32x4 acc[4][4];
    #pragma unroll
    for (int i=0;i<4;++i)
        #pragma unroll
        for (int j=0;j<4;++j) acc[i][j] = zero;
    const unsigned short* Abase = Wb + (size_t)m0*C_;
    const unsigned short* Bbase = xnt + ((size_t)n*S_ + s0) * C_;
    const int row = t >> 1, half = (t & 1) * 16;
    uint4 a0,a1,b0,b1;
    {   // prologue: K-slab 0 -> regs (16 VGPRs only)
        const unsigned short* ap = &Abase[(size_t)row*C_ + half];
        const unsigned short* bp = &Bbase[(size_t)row*C_ + half];
        a0 = ((const uint4*)ap)[0]; a1 = ((const uint4*)ap)[1];
        b0 = ((const uint4*)bp)[0]; b1 = ((const uint4*)bp)[1];
    }
    for (int k0 = 0; k0 < C_; k0 += 32) {
        __syncthreads();                    // previous slab's frag reads complete
        *(uint4*)&As[row*40 + half]     = a0;
        *(uint4*)&As[row*40 + half + 8] = a1;
        *(uint4*)&Bs[row*40 + half]     = b0;
        *(uint4*)&Bs[row*40 + half + 8] = b1;
        if (k0 + 32 < C_) {                 // T14: issue next slab now
            const unsigned short* ap = &Abase[(size_t)row*C_ + k0+32 + half];
            const unsigned short* bp = &Bbase[(size_t)row*C_ + k0+32 + half];
            a0 = ((const uint4*)ap)[0]; a1 = ((const uint4*)ap)[1];
            b0 = ((const uint4*)bp)[0]; b1 = ((const uint4*)bp)[1];
        }
        __syncthreads();                    // LDS visible
        bf16x8 af[4], bfg[4];
        #pragma unroll
        for (int ms=0; ms<4; ++ms) af[ms]  = *(const bf16x8*)&As[(wr+ms*16+l16)*40 + quad*8];
        #pragma unroll
        for (int ns=0; ns<4; ++ns) bfg[ns] = *(const bf16x8*)&Bs[(wc+ns*16+l16)*40 + quad*8];
        if (tr) {
            #pragma unroll
            for (int ms=0; ms<4; ++ms)
                #pragma unroll
                for (int ns=0; ns<4; ++ns)
                    acc[ms][ns] = MFMA16(bfg[ns], af[ms], acc[ms][ns]);  // D rows = s
        } else {
            #pragma unroll
            for (int ms=0; ms<4; ++ms)
                #pragma unroll
                for (int ns=0; ns<4; ++ns)
                    acc[ms][ns] = MFMA16(af[ms], bfg[ns], acc[ms][ns]);  // D rows = o
        }
    }
    __syncthreads();                         // all waves done reading As/Bs
    unsigned short* scr = sh + wv*4096;      // 64x64 shorts per wave
    if (tr) {
        // acc[ms][ns][r]: s_local = ns*16+quad*4+r, d = ms*16+l16 (one g per wave)
        const int g = (m0 + wr) >> 6;
        const float scl = (blockIdx.y < 4) ? SCALEQ : 1.f;
        #pragma unroll
        for (int ms=0; ms<4; ++ms) {
            float bia = bias[m0 + wr + ms*16 + l16];
            #pragma unroll
            for (int ns=0; ns<4; ++ns)
                #pragma unroll
                for (int r=0; r<4; ++r)
                    scr[(ns*16 + quad*4 + r)*64 + ms*16 + l16] =
                        f2b((acc[ms][ns][r] + bia) * scl);
        }
        __asm__ __volatile__("s_waitcnt lgkmcnt(0)" ::: "memory");  // own-wave scratch
        unsigned short* dst = qkT + (((size_t)n*16 + g)*S_ + s0 + wc)*64;
        #pragma unroll
        for (int pass=0; pass<8; ++pass) {
            int sl = pass*8 + (l>>3);
            *(uint4*)&dst[(size_t)sl*64 + (l&7)*8] =
                *(const uint4*)&scr[sl*64 + (l&7)*8];   // 8 full 128B lines/instr
        }
    } else {
        // acc[ms][ns][r]: o_local = ms*16+quad*4+r, s_local = ns*16+l16
        #pragma unroll
        for (int ms=0; ms<4; ++ms)
            #pragma unroll
            for (int ns=0; ns<4; ++ns)
                #pragma unroll
                for (int r=0; r<4; ++r) {
                    int o = m0 + wr + ms*16 + quad*4 + r;
                    scr[(ms*16 + quad*4 + r)*64 + ns*16 + l16] =
                        f2b(acc[ms][ns][r] + bias[o]);
                }
        __asm__ __volatile__("s_waitcnt lgkmcnt(0)" ::: "memory");
        unsigned short* vbase = vbuf + ((size_t)(n*512 + (m0-1024) + wr))*S_ + s0 + wc;
        #pragma unroll
        for (int pass=0; pass<8; ++pass) {
            int vo = pass*8 + (l>>3);
            *(uint4*)&vbase[(size_t)vo*S_ + (l&7)*8] =
                *(const uint4*)&scr[vo*64 + (l&7)*8];   // 128B dense per o-row
        }
    }
}

// ---------------- K4: flash attention (r8 structure + T5 setprio).
// S^T = K Q^T; P in registers (permlane quad redistribution); lsum on the
// matrix pipe; Ks/Vs double-buffered, one barrier per tile; T14 reg-prefetch.
// 4 independent blocks/CU -> waves at different phases: setprio(1) around
// MFMA clusters lets MFMA-issuing waves preempt other blocks' staging (m191).
__global__ __launch_bounds__(256)
void k_attn(const unsigned short* __restrict__ qkT,
            const unsigned short* __restrict__ vbuf,
            unsigned short* __restrict__ yt){
    const int head = blockIdx.x & 63;       // n*8+h  (XCD swizzle: head -> XCD)
    const int qt   = blockIdx.x >> 6;       // 0..15
    const int n = head >> 3, h = head & 7;
    const int t = threadIdx.x, wv = t>>6, l = t&63, quad = l>>4, l16 = l&15;
    const unsigned short* Q = qkT + (((size_t)n*16 + h    )*S_)*64;
    const unsigned short* K = qkT + (((size_t)n*16 + 8 + h)*S_)*64;
    const unsigned short* V = vbuf + ((size_t)n*512 + h*64)*S_;
    __shared__ unsigned short Ks[2][64][72];    // [buf][key][d]
    __shared__ unsigned short Vs[2][64][72];    // [buf][d][key]
    const int qbase = qt*128 + wv*32;
    bf16x8 qf[2][2];
    #pragma unroll
    for (int mt=0; mt<2; ++mt)
        #pragma unroll
        for (int kk=0; kk<2; ++kk)
            qf[mt][kk] = *(const bf16x8*)&Q[(size_t)(qbase+mt*16+l16)*64 + kk*32 + quad*8];
    f32x4 zero = {0.f,0.f,0.f,0.f};
    f32x4 oacc[2][4];
    f32x4 lacc[2] = {zero, zero};
    #pragma unroll
    for (int mt=0;mt<2;++mt)
        #pragma unroll
        for (int dt=0;dt<4;++dt) oacc[mt][dt]=zero;
    bf16x8 onesv;
    #pragma unroll
    for (int i=0;i<8;++i) onesv[i] = (__bf16)1.0f;

    // staging geometry: each thread stages 2 K rows + 2 V rows (16B each).
    const int r0 = t >> 3;              // 0..31
    const int c0 = (t & 7) * 8;         // 0..56 shorts
    const int kOff = r0*64 + c0;
    const int vOff = r0*S_ + c0;
    uint4 ka, kb, va, vb;
    // tile 0 -> buf0
    ka = *(const uint4*)(K + kOff);
    kb = *(const uint4*)(K + kOff + 32*64);
    va = *(const uint4*)(V + vOff);
    vb = *(const uint4*)(V + vOff + (size_t)32*S_);
    *(uint4*)&Ks[0][r0][c0]    = ka;
    *(uint4*)&Ks[0][r0+32][c0] = kb;
    *(uint4*)&Vs[0][r0][c0]    = va;
    *(uint4*)&Vs[0][r0+32][c0] = vb;
    // issue tile 1 (lands in regs during first compute)
    ka = *(const uint4*)(K + 4096 + kOff);
    kb = *(const uint4*)(K + 4096 + kOff + 32*64);
    va = *(const uint4*)(V + 64 + vOff);
    vb = *(const uint4*)(V + 64 + vOff + (size_t)32*S_);
    __syncthreads();

#define ATTN_STEP(RB, WB, KT, DOW, DOL) do {                                   \
    if (DOW) {                                                                 \
        *(uint4*)&Ks[WB][r0][c0]    = ka;  /* vmcnt wait inserted */           \
        *(uint4*)&Ks[WB][r0+32][c0] = kb;                                      \
        *(uint4*)&Vs[WB][r0][c0]    = va;                                      \
        *(uint4*)&Vs[WB][r0+32][c0] = vb;                                      \
        if (DOL) {                                                             \
            const unsigned short* kp = K + (size_t)((KT)+2)*4096;              \
            const unsigned short* vp = V + (size_t)((KT)+2)*64;                \
            ka = *(const uint4*)(kp + kOff);                                   \
            kb = *(const uint4*)(kp + kOff + 32*64);                           \
            va = *(const uint4*)(vp + vOff);                                   \
            vb = *(const uint4*)(vp + vOff + (size_t)32*S_);                   \
        }                                                                      \
    }                                                                          \
    _Pragma("unroll")                                                          \
    for (int ks=0; ks<2; ++ks) {                                               \
        unsigned wp[2][2][2];   /* [ntoff][mt][word] */                        \
        __builtin_amdgcn_s_setprio(1);  /* QK MFMA cluster */                  \
        _Pragma("unroll")                                                      \
        for (int ntoff=0; ntoff<2; ++ntoff) {                                  \
            const int nt = 2*ks + ntoff;                                       \
            bf16x8 kf0 = *(const bf16x8*)&Ks[RB][nt*16 + l16][quad*8];         \
            bf16x8 kf1 = *(const bf16x8*)&Ks[RB][nt*16 + l16][32 + quad*8];    \
            _Pragma("unroll")                                                  \
            for (int mt=0; mt<2; ++mt) {                                       \
                f32x4 s = MFMA16(kf0, qf[mt][0], zero);                        \
                s = MFMA16(kf1, qf[mt][1], s);                                 \
                /* s[r] = S^T[key=nt*16+quad*4+r][q=mt*16+l16], log2 domain */ \
                wp[ntoff][mt][0] = pk2(EXP2(s[0]), EXP2(s[1]));                \
                wp[ntoff][mt][1] = pk2(EXP2(s[2]), EXP2(s[3]));                \
            }                                                                  \
        }                                                                      \
        __builtin_amdgcn_s_setprio(0);  /* permlane/pack window */             \
        bf16x8 pf[2];                                                          \
        _Pragma("unroll")                                                      \
        for (int mt=0; mt<2; ++mt) {                                           \
            unsigned a0 = wp[0][mt][0], b0 = wp[1][mt][0];                     \
            unsigned a1 = wp[0][mt][1], b1 = wp[1][mt][1];                     \
            quad_swap(a0, b0);                                                 \
            quad_swap(a1, b1);                                                 \
            uint4 pw = {a0, a1, b0, b1};                                       \
            pf[mt] = __builtin_bit_cast(bf16x8, pw);                           \
        }                                                                      \
        __builtin_amdgcn_s_setprio(1);  /* PV MFMA cluster */                  \
        lacc[0] = MFMA16(onesv, pf[0], lacc[0]);                               \
        lacc[1] = MFMA16(onesv, pf[1], lacc[1]);                               \
        _Pragma("unroll")                                                      \
        for (int dt=0; dt<4; ++dt) {                                           \
            bf16x8 vf = *(const bf16x8*)&Vs[RB][dt*16 + l16][ks*32 + quad*8];  \
            oacc[0][dt] = MFMA16(vf, pf[0], oacc[0][dt]);                      \
            oacc[1][dt] = MFMA16(vf, pf[1], oacc[1][dt]);                      \
        }                                                                      \
        __builtin_amdgcn_s_setprio(0);                                         \
    }                                                                          \
    __syncthreads();                                                           \
} while(0)

    for (int kt2 = 0; kt2 < 15; ++kt2) {
        const int kt0 = kt2*2;
        ATTN_STEP(0, 1, kt0,   1, 1);
        ATTN_STEP(1, 0, kt0+1, 1, 1);
    }
    ATTN_STEP(0, 1, 30, 1, 0);   // write tile 31, no further loads
    ATTN_STEP(1, 0, 31, 0, 0);   // pure compute
#undef ATTN_STEP

    // lacc rows are identical (ones-A): lane's denom for q=mt*16+l16 is lacc[mt][0]
    float inv[2] = { 1.f / lacc[0][0], 1.f / lacc[1][0] };
    unsigned short* dst = yt + ((size_t)n*S_)*C_;
    #pragma unroll
    for (int mt=0; mt<2; ++mt) {
        int qr = qbase + mt*16 + l16;
        #pragma unroll
        for (int dt=0; dt<4; ++dt) {
            uint2 pk = { pk2(oacc[mt][dt][0]*inv[mt], oacc[mt][dt][1]*inv[mt]),
                         pk2(oacc[mt][dt][2]*inv[mt], oacc[mt][dt][3]*inv[mt]) };
            *(uint2*)&dst[(size_t)qr*C_ + h*64 + dt*16 + quad*4] = pk;
        }
    }
}

// ---------------- K5: out projection, 128x128 tile, BK=32 padded (r4
// structure, measured-best). + bias + residual -> fp32. ----------------
__global__ __launch_bounds__(256)
void k_out(const unsigned short* __restrict__ Wb,
           const float* __restrict__ bias,
           const unsigned short* __restrict__ yt,
           const float* __restrict__ inpt,
           float* __restrict__ out){
    const int n  = blockIdx.z;
    const int m0 = blockIdx.y * 128;
    const int s0 = blockIdx.x * 128;
    const int t = threadIdx.x, wv = t>>6, l = t&63, quad = l>>4, l16 = l&15;
    const int wr = (wv>>1)*64, wc = (wv&1)*64;
    __shared__ unsigned short As[128][40];
    __shared__ unsigned short Bs[128][40];
    f32x4 zero = {0.f,0.f,0.f,0.f};
    f32x4 acc[4][4];
    #pragma unroll
    for (int i=0;i<4;++i)
        #pragma unroll
        for (int j=0;j<4;++j) acc[i][j] = zero;
    const unsigned short* Abase = Wb + (size_t)m0*C_;
    const unsigned short* Bbase = yt + ((size_t)n*S_ + s0) * C_;
    const int row = t >> 1, half = (t & 1) * 16;
    uint4 a0,a1,b0,b1;
    {
        const unsigned short* ap = &Abase[(size_t)row*C_ + half];
        const unsigned short* bp = &Bbase[(size_t)row*C_ + half];
        a0 = ((const uint4*)ap)[0]; a1 = ((const uint4*)ap)[1];
        b0 = ((const uint4*)bp)[0]; b1 = ((const uint4*)bp)[1];
    }
    for (int k0 = 0; k0 < C_; k0 += 32) {
        __syncthreads();
        *(uint4*)&As[row][half]   = a0;
        *(uint4*)&As[row][half+8] = a1;
        *(uint4*)&Bs[row][half]   = b0;
        *(uint4*)&Bs[row][half+8] = b1;
        if (k0 + 32 < C_) {
            const unsigned short* ap = &Abase[(size_t)row*C_ + k0+32 + half];
            const unsigned short* bp = &Bbase[(size_t)row*C_ + k0+32 + half];
            a0 = ((const uint4*)ap)[0]; a1 = ((const uint4*)ap)[1];
            b0 = ((const uint4*)bp)[0]; b1 = ((const uint4*)bp)[1];
        }
        __syncthreads();
        bf16x8 af[4], bfg[4];
        #pragma unroll
        for (int ms=0; ms<4; ++ms) af[ms]  = *(const bf16x8*)&As[wr + ms*16 + l16][quad*8];
        #pragma unroll
        for (int ns=0; ns<4; ++ns) bfg[ns] = *(const bf16x8*)&Bs[wc + ns*16 + l16][quad*8];
        #pragma unroll
        for (int ms=0; ms<4; ++ms)
            #pragma unroll
            for (int ns=0; ns<4; ++ns)
                acc[ms][ns] = MFMA16(af[ms], bfg[ns], acc[ms][ns]);
    }
    #pragma unroll
    for (int ms=0; ms<4; ++ms)
        #pragma unroll
        for (int ns=0; ns<4; ++ns)
            #pragma unroll
            for (int r=0; r<4; ++r) {
                int o = m0 + wr + ms*16 + quad*4 + r;
                int s = s0 + wc + ns*16 + l16;
                size_t idx = ((size_t)n*C_ + o)*S_ + s;
                out[idx] = acc[ms][ns][r] + bias[o] + inpt[idx];
            }
}

extern "C" void kernel_launch(void* const* d_in, const int* in_sizes, int n_in,
                              void* d_out, int out_size, void* d_ws, size_t ws_size,
                              hipStream_t stream) {
    (void)in_sizes; (void)n_in; (void)out_size; (void)ws_size;
    const float* inpt  = (const float*)d_in[0];
    const float* gn_w  = (const float*)d_in[1];
    const float* gn_b  = (const float*)d_in[2];
    const float* qkv_w = (const float*)d_in[3];
    const float* qkv_b = (const float*)d_in[4];
    const float* out_w = (const float*)d_in[5];
    const float* out_b = (const float*)d_in[6];
    float* out = (float*)d_out;

    // ws (48 MiB): xnt [0,16M) (->yt), qkT [16M,48M), stats 64B at qkT tail
    // (temporally disjoint). d_out lends (dead before k_out): vbuf [0,16M),
    // wqkv bf16 [16M,17.5M). wout bf16 reuses qkT base (dead after k_attn).
    char* ws = (char*)d_ws;
    unsigned short* xnt   = (unsigned short*)ws;
    unsigned short* qkT   = (unsigned short*)(ws + ((size_t)16 << 20));
    float*          stats = (float*)(ws + ((size_t)48 << 20) - 64);
    unsigned short* vbuf  = (unsigned short*)d_out;
    unsigned short* wqkv  = (unsigned short*)((char*)d_out + ((size_t)16 << 20));
    unsigned short* wout  = qkT;
    unsigned short* yt    = xnt;

    hipMemsetAsync(stats, 0, 16*sizeof(float), stream);
    k_convert<<<dim3(768),              256, 0, stream>>>(qkv_w, wqkv);
    k_stats <<<dim3(N_*64),             256, 0, stream>>>(inpt, stats);
    k_norm_t<<<dim3(S_/64, C_/64, N_),  256, 0, stream>>>(inpt, gn_w, gn_b, stats, xnt);
    k_qkv   <<<dim3(S_/128, 12, N_),    256, 0, stream>>>(wqkv, qkv_b, xnt, qkT, vbuf);
    k_attn  <<<dim3(1024),              256, 0, stream>>>(qkT, vbuf, yt);
    k_convert<<<dim3(256),              256, 0, stream>>>(out_w, wout);
    k_out   <<<dim3(S_/128, 4, N_),     256, 0, stream>>>(wout, out_b, yt, inpt, out);
}